// Round 16
// baseline (440.910 us; speedup 1.0000x reference)
//
#include <hip/hip_runtime.h>

#define NN 100000
#define NE 1600000
#define NCHUNK 64
#define CHSZ (NE / NCHUNK)   // 25000 edges per chunk
#define NRANGE 8
#define NRPAIR 4             // range-pairs: rp covers ranges {rp, rp+4} packed lo/hi
#define RSZ (NN / NRANGE)    // 12500 nodes per range

typedef short short8 __attribute__((ext_vector_type(8)));
typedef float f32x4 __attribute__((ext_vector_type(4)));

static __device__ __forceinline__ short f2bf(float f) {
    union { float f; unsigned u; } x;
    x.f = f;
    unsigned r = x.u + 0x7FFFu + ((x.u >> 16) & 1u);
    return (short)(r >> 16);
}
static __device__ __forceinline__ float bf2f(unsigned short b) {
    union { unsigned u; float f; } x;
    x.u = ((unsigned)b) << 16;
    return x.f;
}

// unpack 8 bf16 (4 words) and accumulate into 8 f32 chains (exact)
static __device__ __forceinline__ void acc8(const uint4 p, float acc[8]) {
    const unsigned pw[4] = {p.x, p.y, p.z, p.w};
#pragma unroll
    for (int q = 0; q < 4; ++q) {
        union { unsigned u; float f; } lo, hi;
        lo.u = pw[q] << 16;
        hi.u = pw[q] & 0xFFFF0000u;
        acc[q * 2] += lo.f;
        acc[q * 2 + 1] += hi.f;
    }
}

// ---------------------------------------------------------------- per-chunk histograms
// (no global atomics, uint16 H). Two ranges {rp, rp+4} packed per int bin (lo/hi 16b).
__global__ __launch_bounds__(512) void hist_kernel(const int* __restrict__ src,
                                                   const int* __restrict__ dst,
                                                   unsigned short* __restrict__ Hout,
                                                   unsigned short* __restrict__ Hin) {
    __shared__ int hist[RSZ];
    const int c = blockIdx.x, rp = blockIdx.y, z = blockIdx.z;
    const int rlo = rp * RSZ, rhi = (rp + 4) * RSZ;
    for (int j = threadIdx.x; j < RSZ; j += 512) hist[j] = 0;
    __syncthreads();
    const int4* p = (const int4*)((z ? dst : src) + c * CHSZ);
    for (int i = threadIdx.x; i < CHSZ / 4; i += 512) {
        int4 v = p[i];
        int vv[4] = {v.x, v.y, v.z, v.w};
#pragma unroll
        for (int k = 0; k < 4; ++k) {
            unsigned a1 = (unsigned)(vv[k] - rlo);
            if (a1 < RSZ) atomicAdd(&hist[a1], 1);
            unsigned a2 = (unsigned)(vv[k] - rhi);
            if (a2 < RSZ) atomicAdd(&hist[a2], 65536);
        }
    }
    __syncthreads();
    unsigned short* H = (z ? Hin : Hout) + c * NN;
    for (int j = threadIdx.x; j < RSZ; j += 512) {
        int h = hist[j];
        H[rlo + j] = (unsigned short)(h & 0xFFFF);
        H[rhi + j] = (unsigned short)(((unsigned)h) >> 16);
    }
}

// ---------------------------------------------------------------- reduce Hout -> dso; exclusive-scan Hin over chunks -> ind, dsi
__global__ __launch_bounds__(256) void redscan_kernel(const unsigned short* __restrict__ Hout,
                                                      unsigned short* __restrict__ Hin,
                                                      int* __restrict__ ind,
                                                      float* __restrict__ dso,
                                                      float* __restrict__ dsi) {
    int d = blockIdx.x * 256 + threadIdx.x;
    if (d >= NN) return;
    int so = 0;
#pragma unroll 8
    for (int c = 0; c < NCHUNK; ++c) so += Hout[c * NN + d];
    dso[d] = so > 0 ? rsqrtf((float)so) : 1.0f;
    int run = 0;
#pragma unroll 8
    for (int c = 0; c < NCHUNK; ++c) {
        int t = Hin[c * NN + d];
        Hin[c * NN + d] = (unsigned short)run;
        run += t;
    }
    ind[d] = run;
    dsi[d] = run > 0 ? rsqrtf((float)run) : 1.0f;
}

// ---------------------------------------------------------------- scan (row_start)
__global__ __launch_bounds__(256) void scan1_kernel(const int* __restrict__ deg,
                                                    int* __restrict__ rs,
                                                    int* __restrict__ bsum, int N) {
    __shared__ int lds[256];
    int t = threadIdx.x, b = blockIdx.x;
    int base = b * 1024 + t * 4;
    int v0 = 0, v1 = 0, v2 = 0, v3 = 0;
    if (base + 0 < N) v0 = deg[base + 0];
    if (base + 1 < N) v1 = deg[base + 1];
    if (base + 2 < N) v2 = deg[base + 2];
    if (base + 3 < N) v3 = deg[base + 3];
    lds[t] = v0 + v1 + v2 + v3;
    __syncthreads();
    for (int off = 1; off < 256; off <<= 1) {
        int add = (t >= off) ? lds[t - off] : 0;
        __syncthreads();
        lds[t] += add;
        __syncthreads();
    }
    int excl = (t > 0) ? lds[t - 1] : 0;
    if (t == 255) bsum[b] = lds[255];
    int r0 = excl + v0, r1 = r0 + v1, r2 = r1 + v2, r3 = r2 + v3;
    if (base + 0 < N) rs[base + 0] = r0;
    if (base + 1 < N) rs[base + 1] = r1;
    if (base + 2 < N) rs[base + 2] = r2;
    if (base + 3 < N) rs[base + 3] = r3;
}

__global__ void scan2_kernel(int* __restrict__ bsum, int NB) {
    __shared__ int lds[128];
    int t = threadIdx.x;
    lds[t] = (t < NB) ? bsum[t] : 0;
    __syncthreads();
    for (int off = 1; off < 128; off <<= 1) {
        int add = (t >= off) ? lds[t - off] : 0;
        __syncthreads();
        lds[t] += add;
        __syncthreads();
    }
    if (t < NB) bsum[t] = (t > 0) ? lds[t - 1] : 0;
}

// scan3: rs = exclusive row start (no H fold; fill adds rs on the fly)
__global__ void scan3_kernel(int* __restrict__ rs, const int* __restrict__ deg,
                             const int* __restrict__ bsum, int N) {
    int i = blockIdx.x * blockDim.x + threadIdx.x;
    if (i < N) rs[i] = rs[i] - deg[i] + bsum[i >> 10];
}

// ---------------------------------------------------------------- CSR fill (counting sort, no global atomics)
__global__ __launch_bounds__(512) void fill_kernel(const int* __restrict__ src,
                                                   const int* __restrict__ dst,
                                                   const unsigned short* __restrict__ Hin,
                                                   const int* __restrict__ rs,
                                                   int* __restrict__ eidx) {
    __shared__ int cnt[RSZ];
    const int c = blockIdx.x >> 2, rp = blockIdx.x & 3;
    const int rlo = rp * RSZ, rhi = (rp + 4) * RSZ;
    for (int j = threadIdx.x; j < RSZ; j += 512) cnt[j] = 0;
    __syncthreads();
    const int4* ps = (const int4*)(src + c * CHSZ);
    const int4* pd = (const int4*)(dst + c * CHSZ);
    const unsigned short* Hc = Hin + c * NN;
    for (int i = threadIdx.x; i < CHSZ / 4; i += 512) {
        int4 s4 = ps[i];
        int4 d4 = pd[i];
        int ss[4] = {s4.x, s4.y, s4.z, s4.w};
        int dd[4] = {d4.x, d4.y, d4.z, d4.w};
#pragma unroll
        for (int k = 0; k < 4; ++k) {
            const int d = dd[k];
            unsigned a1 = (unsigned)(d - rlo);
            if (a1 < RSZ) {
                int old = atomicAdd(&cnt[a1], 1);
                eidx[rs[d] + (int)Hc[d] + (old & 0xFFFF)] = ss[k];
            }
            unsigned a2 = (unsigned)(d - rhi);
            if (a2 < RSZ) {
                int old = atomicAdd(&cnt[a2], 65536);
                eidx[rs[d] + (int)Hc[d] + (int)(((unsigned)old) >> 16)] = ss[k];
            }
        }
    }
}

// ---------------------------------------------------------------- weight prep: bf16 transpose WT[n][k], pad rows to npad (zeros)
struct PrepBatch {
    const float* src[6];
    unsigned short* dst[6];
    int nout[6];
    int npad[6];
};
__global__ __launch_bounds__(256) void prep_kernel(PrepBatch pb) {
    int m = blockIdx.y;
    int npad = pb.npad[m], nout = pb.nout[m];
    int i = blockIdx.x * 256 + threadIdx.x;
    if (i < 128 * npad) {
        int k = i / npad, n = i - k * npad;
        float v = (n < nout) ? pb.src[m][k * nout + n] : 0.0f;
        pb.dst[m][n * 128 + k] = (unsigned short)f2bf(v);
    }
}

// ---------------------------------------------------------------- MFMA dual GEMM v2 (B-in-registers, X staged bf16 in LDS)
template <int CPW, bool BN, bool BIAS, bool XBF16, bool VBF16>
__global__ __launch_bounds__(256) void gemm_mfma2_kernel(
    const void* __restrict__ X, const unsigned short* __restrict__ WT,
    const unsigned short* __restrict__ LT, const float* __restrict__ bias,
    const float* __restrict__ scale, const float* __restrict__ shift,
    const float* __restrict__ dso, unsigned short* __restrict__ U, void* __restrict__ V,
    int N, int upitch, int ucols, int vpitch, int vcols) {
    constexpr int NCT = CPW / 16;
    __shared__ __align__(16) unsigned short Xs[64][128];  // 16 KB, granule-swizzled
    const int tid = threadIdx.x;
    const long rb = (long)blockIdx.x * 64;

#pragma unroll
    for (int i = 0; i < 4; ++i) {
        const int idx = i * 256 + tid;
        const int r = idx >> 4, g = idx & 15;
        const long gr = rb + r;
        float xs[8];
        if (gr < N) {
            if (XBF16) {
                const unsigned short* Xh = (const unsigned short*)X;
                short8 raw = *(const short8*)&Xh[gr * 128 + g * 8];
#pragma unroll
                for (int j = 0; j < 8; ++j) xs[j] = bf2f((unsigned short)raw[j]);
            } else {
                const float* Xf = (const float*)X;
                float4 a0 = *(const float4*)&Xf[gr * 128 + g * 8];
                float4 a1 = *(const float4*)&Xf[gr * 128 + g * 8 + 4];
                xs[0] = a0.x; xs[1] = a0.y; xs[2] = a0.z; xs[3] = a0.w;
                xs[4] = a1.x; xs[5] = a1.y; xs[6] = a1.z; xs[7] = a1.w;
            }
            if (BN) {
                float4 s0 = *(const float4*)&scale[g * 8];
                float4 s1 = *(const float4*)&scale[g * 8 + 4];
                float4 h0 = *(const float4*)&shift[g * 8];
                float4 h1 = *(const float4*)&shift[g * 8 + 4];
                float ss[8] = {s0.x, s0.y, s0.z, s0.w, s1.x, s1.y, s1.z, s1.w};
                float hh[8] = {h0.x, h0.y, h0.z, h0.w, h1.x, h1.y, h1.z, h1.w};
#pragma unroll
                for (int j = 0; j < 8; ++j) xs[j] = fmaxf(fmaf(xs[j], ss[j], hh[j]), 0.0f);
            }
        } else {
#pragma unroll
            for (int j = 0; j < 8; ++j) xs[j] = 0.0f;
        }
        short8 pk;
#pragma unroll
        for (int j = 0; j < 8; ++j) pk[j] = f2bf(xs[j]);
        const int gp = g ^ (r & 7);
        *(short8*)&Xs[r][gp * 8] = pk;
    }

    const int w = tid >> 6, l = tid & 63;
    const int lr = l & 15, kg = l >> 4;
    const unsigned short* BT = (w < 2) ? WT : LT;
    const int c0 = (w & 1) * CPW;
    short8 bfr[NCT][4];
#pragma unroll
    for (int ct = 0; ct < NCT; ++ct)
#pragma unroll
        for (int kc = 0; kc < 4; ++kc)
            bfr[ct][kc] = *(const short8*)&BT[(c0 + ct * 16 + lr) * 128 + kc * 32 + kg * 8];

    __syncthreads();

#pragma unroll 1
    for (int rt = 0; rt < 4; ++rt) {
        f32x4 acc[NCT];
#pragma unroll
        for (int ct = 0; ct < NCT; ++ct) acc[ct] = (f32x4)(0.0f);
        const int xrow = rt * 16 + lr;
#pragma unroll
        for (int kc = 0; kc < 4; ++kc) {
            const int p = (kc * 4 + kg) ^ (lr & 7);
            short8 av = *(const short8*)&Xs[xrow][p * 8];
#pragma unroll
            for (int ct = 0; ct < NCT; ++ct)
                acc[ct] = __builtin_amdgcn_mfma_f32_16x16x32_bf16(av, bfr[ct][kc], acc[ct], 0, 0, 0);
        }
        const long r0 = rb + rt * 16 + kg * 4;
        if (w < 2) {
#pragma unroll
            for (int ct = 0; ct < NCT; ++ct) {
                const int c = c0 + ct * 16 + lr;
                if (c < ucols) {
#pragma unroll
                    for (int r = 0; r < 4; ++r) {
                        const long rr = r0 + r;
                        if (rr < N) U[rr * upitch + c] = (unsigned short)f2bf(acc[ct][r] * dso[rr]);
                    }
                }
            }
        } else {
#pragma unroll
            for (int ct = 0; ct < NCT; ++ct) {
                const int c = c0 + ct * 16 + lr;
                if (c < vcols) {
#pragma unroll
                    for (int r = 0; r < 4; ++r) {
                        const long rr = r0 + r;
                        if (rr < N) {
                            float v = acc[ct][r];
                            if (BIAS) v += bias[c];
                            if (VBF16)
                                ((unsigned short*)V)[rr * vpitch + c] = (unsigned short)f2bf(v);
                            else
                                ((float*)V)[rr * vpitch + c] = v;
                        }
                    }
                }
            }
        }
    }
}

// ---------------------------------------------------------------- SpMM v5 (bf16 gather, NPW nodes per wave, register reduce,
// deep load ladder 8/4/1 for max loads-in-flight per wave)
// LPN = 64/NPW lanes per node; G = LPN/LPR edge groups. Reduce: xor-ladder over G.
// ABF16: addB bf16 (else f32); YBF16: Y bf16 (else f32); both pitch D.
template <int D, int PITCH, int LPR, bool ABF16, bool YBF16, int UCH, int NPW>
__global__ __launch_bounds__(256) void spmm_bf16_kernel(
    const unsigned short* __restrict__ Uin, const void* __restrict__ addB,
    void* __restrict__ Y, const int* __restrict__ eidx, const int* __restrict__ rs,
    const int* __restrict__ deg, const float* __restrict__ dsi, int N) {
    constexpr int LPN = 64 / NPW;   // lanes per node
    constexpr int G = LPN / LPR;    // edge groups per node
    __shared__ __align__(16) int sE[4][64];
    const int wvloc = threadIdx.x >> 6;
    const int lane = threadIdx.x & 63;
    const int ll = lane & (LPN - 1);       // lane within node group
    const int nbase = lane - ll;           // node group base lane
    const int lr = ll & (LPR - 1);         // position within row
    const int g = ll / LPR;                // edge group within node
    const int wv = (blockIdx.x * 4 + wvloc) * NPW + (lane / LPN);
    if (wv >= N) return;
    const bool act = (UCH == LPR * 8) || (lr * 8 < UCH);
    const int start = rs[wv];
    const int dg = deg[wv];
    const float di = dsi[wv];

    // hoisted epilogue inputs (independent of gathers)
    const bool wract = (ll < LPR) && (ll * 8 < D);
    const long o = (long)wv * D + ll * 8;
    short8 braw = {};
    f32x4 b0 = (f32x4)(0.0f), b1 = (f32x4)(0.0f);
    if (wract) {
        if (ABF16) {
            braw = *(const short8*)&((const unsigned short*)addB)[o];
        } else {
            b0 = *(const f32x4*)&((const float*)addB)[o];
            b1 = *(const f32x4*)&((const float*)addB)[o + 4];
        }
    }

    float acc[8] = {};
    for (int j0 = 0; j0 < dg; j0 += LPN) {
        const int m = min(LPN, dg - j0);
        if (ll < m) sE[wvloc][lane] = eidx[start + j0 + ll];
        asm volatile("s_waitcnt lgkmcnt(0)" ::: "memory");
        int j = g;
#pragma unroll 1
        for (; j + 7 * G < m; j += 8 * G) {
            if (act) {
                uint4 p0, p1, p2, p3, p4, p5, p6, p7;
                {
                    const int s0 = sE[wvloc][nbase + j];
                    const int s1 = sE[wvloc][nbase + j + G];
                    const int s2 = sE[wvloc][nbase + j + 2 * G];
                    const int s3 = sE[wvloc][nbase + j + 3 * G];
                    const int s4 = sE[wvloc][nbase + j + 4 * G];
                    const int s5 = sE[wvloc][nbase + j + 5 * G];
                    const int s6 = sE[wvloc][nbase + j + 6 * G];
                    const int s7 = sE[wvloc][nbase + j + 7 * G];
                    p0 = *(const uint4*)&Uin[(long)s0 * PITCH + lr * 8];
                    p1 = *(const uint4*)&Uin[(long)s1 * PITCH + lr * 8];
                    p2 = *(const uint4*)&Uin[(long)s2 * PITCH + lr * 8];
                    p3 = *(const uint4*)&Uin[(long)s3 * PITCH + lr * 8];
                    p4 = *(const uint4*)&Uin[(long)s4 * PITCH + lr * 8];
                    p5 = *(const uint4*)&Uin[(long)s5 * PITCH + lr * 8];
                    p6 = *(const uint4*)&Uin[(long)s6 * PITCH + lr * 8];
                    p7 = *(const uint4*)&Uin[(long)s7 * PITCH + lr * 8];
                }
                acc8(p0, acc);
                acc8(p1, acc);
                acc8(p2, acc);
                acc8(p3, acc);
                acc8(p4, acc);
                acc8(p5, acc);
                acc8(p6, acc);
                acc8(p7, acc);
            }
        }
#pragma unroll 1
        for (; j + 3 * G < m; j += 4 * G) {
            if (act) {
                const int s0 = sE[wvloc][nbase + j];
                const int s1 = sE[wvloc][nbase + j + G];
                const int s2 = sE[wvloc][nbase + j + 2 * G];
                const int s3 = sE[wvloc][nbase + j + 3 * G];
                const uint4 p0 = *(const uint4*)&Uin[(long)s0 * PITCH + lr * 8];
                const uint4 p1 = *(const uint4*)&Uin[(long)s1 * PITCH + lr * 8];
                const uint4 p2 = *(const uint4*)&Uin[(long)s2 * PITCH + lr * 8];
                const uint4 p3 = *(const uint4*)&Uin[(long)s3 * PITCH + lr * 8];
                acc8(p0, acc);
                acc8(p1, acc);
                acc8(p2, acc);
                acc8(p3, acc);
            }
        }
#pragma unroll 1
        for (; j < m; j += G) {
            if (act) {
                const int s = sE[wvloc][nbase + j];
                const uint4 p = *(const uint4*)&Uin[(long)s * PITCH + lr * 8];
                acc8(p, acc);
            }
        }
    }
    // cross-group reduce in registers (xor-ladder within node group; exec-safe)
    if (G >= 2) {
#pragma unroll
        for (int off = LPR; off < LPN; off <<= 1) {
#pragma unroll
            for (int q = 0; q < 8; ++q) acc[q] += __shfl_xor(acc[q], off);
        }
    }
    if (wract) {
        f32x4 r0 = {acc[0], acc[1], acc[2], acc[3]};
        f32x4 r1 = {acc[4], acc[5], acc[6], acc[7]};
        if (YBF16) {
            short8 yv;
            if (ABF16) {
#pragma unroll
                for (int j = 0; j < 4; ++j)
                    yv[j] = f2bf(bf2f((unsigned short)braw[j]) + r0[j] * di);
#pragma unroll
                for (int j = 0; j < 4; ++j)
                    yv[4 + j] = f2bf(bf2f((unsigned short)braw[4 + j]) + r1[j] * di);
            } else {
#pragma unroll
                for (int j = 0; j < 4; ++j) yv[j] = f2bf(b0[j] + r0[j] * di);
#pragma unroll
                for (int j = 0; j < 4; ++j) yv[4 + j] = f2bf(b1[j] + r1[j] * di);
            }
            *(short8*)&((unsigned short*)Y)[o] = yv;
        } else {
            f32x4 y0, y1;
            if (ABF16) {
#pragma unroll
                for (int j = 0; j < 4; ++j) y0[j] = bf2f((unsigned short)braw[j]) + r0[j] * di;
#pragma unroll
                for (int j = 0; j < 4; ++j) y1[j] = bf2f((unsigned short)braw[4 + j]) + r1[j] * di;
            } else {
                y0 = b0 + r0 * di;
                y1 = b1 + r1 * di;
            }
            *(f32x4*)&((float*)Y)[o] = y0;
            *(f32x4*)&((float*)Y)[o + 4] = y1;
        }
    }
}

// ---------------------------------------------------------------- BN stats over bf16 P (sum, sumsq per channel)
__global__ __launch_bounds__(256) void bnstats_kernel(const unsigned short* __restrict__ P,
                                                      float* __restrict__ sum,
                                                      float* __restrict__ sq, int N) {
    int c = threadIdx.x & 127;
    int half = threadIdx.x >> 7;
    float s = 0.f, q = 0.f;
    for (long r = blockIdx.x * 2 + half; r < N; r += gridDim.x * 2) {
        float v = bf2f(P[r * 128 + c]);
        s += v;
        q += v * v;
    }
    __shared__ float ls[256], lq[256];
    ls[threadIdx.x] = s;
    lq[threadIdx.x] = q;
    __syncthreads();
    if (threadIdx.x < 128) {
        s = ls[threadIdx.x] + ls[threadIdx.x + 128];
        q = lq[threadIdx.x] + lq[threadIdx.x + 128];
        atomicAdd(&sum[c], s);
        atomicAdd(&sq[c], q);
    }
}

// bnfinal also re-zeroes sum/sq (so the next bnstats needs no memset; replay-safe)
__global__ void bnfinal_kernel(float* __restrict__ sum, float* __restrict__ sq,
                               const float* __restrict__ g, const float* __restrict__ be,
                               float* __restrict__ scale, float* __restrict__ shift, float invN) {
    int c = threadIdx.x;  // 128 threads
    float mu = sum[c] * invN;
    float var = sq[c] * invN - mu * mu;
    float sc = g[c] * rsqrtf(var + 1e-5f);
    scale[c] = sc;
    shift[c] = be[c] - mu * sc;
    sum[c] = 0.0f;
    sq[c] = 0.0f;
}

// ---------------------------------------------------------------- launch
extern "C" void kernel_launch(void* const* d_in, const int* in_sizes, int n_in,
                              void* d_out, int out_size, void* d_ws, size_t ws_size,
                              hipStream_t stream) {
    const float* feat = (const float*)d_in[0];
    const int* src = (const int*)d_in[1];
    const int* dst = (const int*)d_in[2];
    const float* W0 = (const float*)d_in[3];
    const float* L0 = (const float*)d_in[4];
    const float* W1 = (const float*)d_in[5];
    const float* L1 = (const float*)d_in[6];
    const float* W2 = (const float*)d_in[7];
    const float* L2 = (const float*)d_in[8];
    const float* b2 = (const float*)d_in[9];
    const float* g0 = (const float*)d_in[10];
    const float* be0 = (const float*)d_in[11];
    const float* g1 = (const float*)d_in[12];
    const float* be1 = (const float*)d_in[13];
    float* out = (float*)d_out;

    char* w = (char*)d_ws;
    unsigned short* bufP = (unsigned short*)(w + 0);          // 25,600,000 B (bf16 P0/P1)
    unsigned short* bufU = (unsigned short*)(w + 25600000);   // 25,600,000 B (bf16 U)
    unsigned short* bufV = (unsigned short*)(w + 51200000);   // 25,600,000 B (bf16 V, all layers)
    int* eidx = (int*)(w + 76800000);                         // 6,400,000 B
    int* ind = (int*)(w + 83200000);                          // 400,000 B
    float* dso = (float*)(w + 83600000);                      // 400,000 B
    float* dsi = (float*)(w + 84000000);                      // 400,000 B
    int* rs = (int*)(w + 84400000);                           // 400,000 B
    int* bsum = (int*)(w + 84800000);                         // 512 B
    float* bnsum = (float*)(w + 84801024);                    // 512 B
    float* bnsq = (float*)(w + 84801536);                     // 512 B
    float* scl = (float*)(w + 84802048);                      // 512 B
    float* sht = (float*)(w + 84802560);                      // 512 B
    unsigned short* W0T = (unsigned short*)(w + 84803072);    // 32768 B each (128x128 bf16)
    unsigned short* L0T = (unsigned short*)(w + 84835840);
    unsigned short* W1T = (unsigned short*)(w + 84868608);
    unsigned short* L1T = (unsigned short*)(w + 84901376);
    unsigned short* W2T = (unsigned short*)(w + 84934144);    // 64x128 bf16 = 16384 B
    unsigned short* L2T = (unsigned short*)(w + 84950528);

    // uint16 H matrices (NCHUNK=64: 12.8 MB each) alias later-written buffers:
    unsigned short* Hout = bufP;  // dead after redscan; bufP first written by spmm0
    unsigned short* Hin = bufU;   // dead after fill; bufU first written by gemm0 (after fill)

    const int N = NN;
    const int NB = (N + 1023) / 1024;  // 98
    const int GB = (N + 63) / 64;      // 1563 gemm blocks
    const int SB2 = (N + 7) / 8;       // 12500 spmm blocks (4 waves x 2 nodes)

    // weight prep (independent of graph build)
    PrepBatch pb;
    pb.src[0] = W0; pb.dst[0] = W0T; pb.nout[0] = 128; pb.npad[0] = 128;
    pb.src[1] = L0; pb.dst[1] = L0T; pb.nout[1] = 128; pb.npad[1] = 128;
    pb.src[2] = W1; pb.dst[2] = W1T; pb.nout[2] = 128; pb.npad[2] = 128;
    pb.src[3] = L1; pb.dst[3] = L1T; pb.nout[3] = 128; pb.npad[3] = 128;
    pb.src[4] = W2; pb.dst[4] = W2T; pb.nout[4] = 40;  pb.npad[4] = 64;
    pb.src[5] = L2; pb.dst[5] = L2T; pb.nout[5] = 40;  pb.npad[5] = 64;
    prep_kernel<<<dim3(64, 6), 256, 0, stream>>>(pb);

    // graph build (no global atomics; range-paired histograms, NCHUNK=64)
    hist_kernel<<<dim3(NCHUNK, NRPAIR, 2), 512, 0, stream>>>(src, dst, Hout, Hin);
    redscan_kernel<<<(N + 255) / 256, 256, 0, stream>>>(Hout, Hin, ind, dso, dsi);
    scan1_kernel<<<NB, 256, 0, stream>>>(ind, rs, bsum, N);
    scan2_kernel<<<1, 128, 0, stream>>>(bsum, NB);
    scan3_kernel<<<(N + 255) / 256, 256, 0, stream>>>(rs, ind, bsum, N);
    fill_kernel<<<NCHUNK * NRPAIR, 512, 0, stream>>>(src, dst, Hin, rs, eidx);

    // zero BN accumulators once; bnfinal re-zeroes after each use
    hipMemsetAsync(bnsum, 0, 1024, stream);

    // ---- layer 0: U0 = dso*(feat@W0) -> bufU, V0 = feat@L0 -> bufV (bf16); P0 = spmm(U0)+V0 -> bufP (bf16)
    gemm_mfma2_kernel<64, false, false, false, true><<<GB, 256, 0, stream>>>(
        feat, W0T, L0T, nullptr, nullptr, nullptr, dso, bufU, bufV, N, 128, 128, 128, 128);
    spmm_bf16_kernel<128, 128, 16, true, true, 128, 2><<<SB2, 256, 0, stream>>>(
        bufU, bufV, bufP, eidx, rs, ind, dsi, N);
    bnstats_kernel<<<1024, 256, 0, stream>>>(bufP, bnsum, bnsq, N);
    bnfinal_kernel<<<1, 128, 0, stream>>>(bnsum, bnsq, g0, be0, scl, sht, 1.0f / N);

    // ---- layer 1: X = bnrelu(P0) bf16; U -> bufU, V -> bufV; P1 = spmm+V -> bufP
    gemm_mfma2_kernel<64, true, false, true, true><<<GB, 256, 0, stream>>>(
        bufP, W1T, L1T, nullptr, scl, sht, dso, bufU, bufV, N, 128, 128, 128, 128);
    spmm_bf16_kernel<128, 128, 16, true, true, 128, 2><<<SB2, 256, 0, stream>>>(
        bufU, bufV, bufP, eidx, rs, ind, dsi, N);
    bnstats_kernel<<<1024, 256, 0, stream>>>(bufP, bnsum, bnsq, N);
    bnfinal_kernel<<<1, 128, 0, stream>>>(bnsum, bnsq, g1, be1, scl, sht, 1.0f / N);

    // ---- layer 2: U2 pitch 40 bf16 (cols 0..39) -> bufU, V2 = X@L2 + b2 (bf16, pitch 40) -> bufV
    gemm_mfma2_kernel<32, true, true, true, true><<<GB, 256, 0, stream>>>(
        bufP, W2T, L2T, b2, scl, sht, dso, bufU, bufV, N, 40, 40, 40, 40);
    spmm_bf16_kernel<40, 40, 8, true, false, 40, 2><<<SB2, 256, 0, stream>>>(
        bufU, bufV, out, eidx, rs, ind, dsi, N);
}

// Round 17
// 413.073 us; speedup vs baseline: 1.0674x; 1.0674x over previous
//
#include <hip/hip_runtime.h>

#define NN 100000
#define NE 1600000
#define NCHUNK 64
#define CHSZ (NE / NCHUNK)   // 25000 edges per chunk
#define NRANGE 8
#define NRPAIR 4             // range-pairs: rp covers ranges {rp, rp+4} packed lo/hi
#define RSZ (NN / NRANGE)    // 12500 nodes per range

typedef short short8 __attribute__((ext_vector_type(8)));
typedef float f32x4 __attribute__((ext_vector_type(4)));

static __device__ __forceinline__ short f2bf(float f) {
    union { float f; unsigned u; } x;
    x.f = f;
    unsigned r = x.u + 0x7FFFu + ((x.u >> 16) & 1u);
    return (short)(r >> 16);
}
static __device__ __forceinline__ float bf2f(unsigned short b) {
    union { unsigned u; float f; } x;
    x.u = ((unsigned)b) << 16;
    return x.f;
}

// unpack 8 bf16 (4 words) and accumulate into 8 f32 chains (exact)
static __device__ __forceinline__ void acc8(const uint4 p, float acc[8]) {
    const unsigned pw[4] = {p.x, p.y, p.z, p.w};
#pragma unroll
    for (int q = 0; q < 4; ++q) {
        union { unsigned u; float f; } lo, hi;
        lo.u = pw[q] << 16;
        hi.u = pw[q] & 0xFFFF0000u;
        acc[q * 2] += lo.f;
        acc[q * 2 + 1] += hi.f;
    }
}

// ---------------------------------------------------------------- per-chunk histograms
// (no global atomics, uint16 H). Two ranges {rp, rp+4} packed per int bin (lo/hi 16b).
__global__ __launch_bounds__(512) void hist_kernel(const int* __restrict__ src,
                                                   const int* __restrict__ dst,
                                                   unsigned short* __restrict__ Hout,
                                                   unsigned short* __restrict__ Hin) {
    __shared__ int hist[RSZ];
    const int c = blockIdx.x, rp = blockIdx.y, z = blockIdx.z;
    const int rlo = rp * RSZ, rhi = (rp + 4) * RSZ;
    for (int j = threadIdx.x; j < RSZ; j += 512) hist[j] = 0;
    __syncthreads();
    const int4* p = (const int4*)((z ? dst : src) + c * CHSZ);
    for (int i = threadIdx.x; i < CHSZ / 4; i += 512) {
        int4 v = p[i];
        int vv[4] = {v.x, v.y, v.z, v.w};
#pragma unroll
        for (int k = 0; k < 4; ++k) {
            unsigned a1 = (unsigned)(vv[k] - rlo);
            if (a1 < RSZ) atomicAdd(&hist[a1], 1);
            unsigned a2 = (unsigned)(vv[k] - rhi);
            if (a2 < RSZ) atomicAdd(&hist[a2], 65536);
        }
    }
    __syncthreads();
    unsigned short* H = (z ? Hin : Hout) + c * NN;
    for (int j = threadIdx.x; j < RSZ; j += 512) {
        int h = hist[j];
        H[rlo + j] = (unsigned short)(h & 0xFFFF);
        H[rhi + j] = (unsigned short)(((unsigned)h) >> 16);
    }
}

// ---------------------------------------------------------------- reduce Hout -> dso; exclusive-scan Hin over chunks -> ind, dsi
__global__ __launch_bounds__(256) void redscan_kernel(const unsigned short* __restrict__ Hout,
                                                      unsigned short* __restrict__ Hin,
                                                      int* __restrict__ ind,
                                                      float* __restrict__ dso,
                                                      float* __restrict__ dsi) {
    int d = blockIdx.x * 256 + threadIdx.x;
    if (d >= NN) return;
    int so = 0;
#pragma unroll 8
    for (int c = 0; c < NCHUNK; ++c) so += Hout[c * NN + d];
    dso[d] = so > 0 ? rsqrtf((float)so) : 1.0f;
    int run = 0;
#pragma unroll 8
    for (int c = 0; c < NCHUNK; ++c) {
        int t = Hin[c * NN + d];
        Hin[c * NN + d] = (unsigned short)run;
        run += t;
    }
    ind[d] = run;
    dsi[d] = run > 0 ? rsqrtf((float)run) : 1.0f;
}

// ---------------------------------------------------------------- scan (row_start)
__global__ __launch_bounds__(256) void scan1_kernel(const int* __restrict__ deg,
                                                    int* __restrict__ rs,
                                                    int* __restrict__ bsum, int N) {
    __shared__ int lds[256];
    int t = threadIdx.x, b = blockIdx.x;
    int base = b * 1024 + t * 4;
    int v0 = 0, v1 = 0, v2 = 0, v3 = 0;
    if (base + 0 < N) v0 = deg[base + 0];
    if (base + 1 < N) v1 = deg[base + 1];
    if (base + 2 < N) v2 = deg[base + 2];
    if (base + 3 < N) v3 = deg[base + 3];
    lds[t] = v0 + v1 + v2 + v3;
    __syncthreads();
    for (int off = 1; off < 256; off <<= 1) {
        int add = (t >= off) ? lds[t - off] : 0;
        __syncthreads();
        lds[t] += add;
        __syncthreads();
    }
    int excl = (t > 0) ? lds[t - 1] : 0;
    if (t == 255) bsum[b] = lds[255];
    int r0 = excl + v0, r1 = r0 + v1, r2 = r1 + v2, r3 = r2 + v3;
    if (base + 0 < N) rs[base + 0] = r0;
    if (base + 1 < N) rs[base + 1] = r1;
    if (base + 2 < N) rs[base + 2] = r2;
    if (base + 3 < N) rs[base + 3] = r3;
}

__global__ void scan2_kernel(int* __restrict__ bsum, int NB) {
    __shared__ int lds[128];
    int t = threadIdx.x;
    lds[t] = (t < NB) ? bsum[t] : 0;
    __syncthreads();
    for (int off = 1; off < 128; off <<= 1) {
        int add = (t >= off) ? lds[t - off] : 0;
        __syncthreads();
        lds[t] += add;
        __syncthreads();
    }
    if (t < NB) bsum[t] = (t > 0) ? lds[t - 1] : 0;
}

// scan3: rs = exclusive row start (no H fold; fill adds rs on the fly)
__global__ void scan3_kernel(int* __restrict__ rs, const int* __restrict__ deg,
                             const int* __restrict__ bsum, int N) {
    int i = blockIdx.x * blockDim.x + threadIdx.x;
    if (i < N) rs[i] = rs[i] - deg[i] + bsum[i >> 10];
}

// ---------------------------------------------------------------- CSR fill (counting sort, no global atomics)
__global__ __launch_bounds__(512) void fill_kernel(const int* __restrict__ src,
                                                   const int* __restrict__ dst,
                                                   const unsigned short* __restrict__ Hin,
                                                   const int* __restrict__ rs,
                                                   int* __restrict__ eidx) {
    __shared__ int cnt[RSZ];
    const int c = blockIdx.x >> 2, rp = blockIdx.x & 3;
    const int rlo = rp * RSZ, rhi = (rp + 4) * RSZ;
    for (int j = threadIdx.x; j < RSZ; j += 512) cnt[j] = 0;
    __syncthreads();
    const int4* ps = (const int4*)(src + c * CHSZ);
    const int4* pd = (const int4*)(dst + c * CHSZ);
    const unsigned short* Hc = Hin + c * NN;
    for (int i = threadIdx.x; i < CHSZ / 4; i += 512) {
        int4 s4 = ps[i];
        int4 d4 = pd[i];
        int ss[4] = {s4.x, s4.y, s4.z, s4.w};
        int dd[4] = {d4.x, d4.y, d4.z, d4.w};
#pragma unroll
        for (int k = 0; k < 4; ++k) {
            const int d = dd[k];
            unsigned a1 = (unsigned)(d - rlo);
            if (a1 < RSZ) {
                int old = atomicAdd(&cnt[a1], 1);
                eidx[rs[d] + (int)Hc[d] + (old & 0xFFFF)] = ss[k];
            }
            unsigned a2 = (unsigned)(d - rhi);
            if (a2 < RSZ) {
                int old = atomicAdd(&cnt[a2], 65536);
                eidx[rs[d] + (int)Hc[d] + (int)(((unsigned)old) >> 16)] = ss[k];
            }
        }
    }
}

// ---------------------------------------------------------------- weight prep: FRAGMENT-MAJOR bf16 layout
// FB[slot][lane][8]: slot = (h*NCT + ct)*4 + kc (NCT = npad/32, h = wave-half).
// value[e] = W[k][n], n = h*(npad/2) + ct*16 + (lane&15), k = kc*32 + (lane>>4)*8 + e.
// Every gemm B-frag load becomes one contiguous 1 KB burst.
struct PrepBatch {
    const float* src[6];
    unsigned short* dst[6];
    int nout[6];
    int npad[6];
};
__global__ __launch_bounds__(256) void prep_kernel(PrepBatch pb) {
    int m = blockIdx.y;
    int npad = pb.npad[m], nout = pb.nout[m];
    int i = blockIdx.x * 256 + threadIdx.x;
    if (i < 128 * npad) {
        int e = i & 7;
        int lane = (i >> 3) & 63;
        int slot = i >> 9;
        int nct = npad >> 5;         // fragments per wave-half
        int per = nct << 2;          // slots per half
        int h = slot / per;
        int rem = slot - h * per;
        int ct = rem >> 2, kc = rem & 3;
        int n = h * (nct << 4) + ct * 16 + (lane & 15);
        int k = kc * 32 + (lane >> 4) * 8 + e;
        float v = (n < nout) ? pb.src[m][k * nout + n] : 0.0f;
        pb.dst[m][i] = (unsigned short)f2bf(v);
    }
}

// ---------------------------------------------------------------- MFMA dual GEMM v2 (B-in-registers, X staged bf16 in LDS)
// B fragments read from fragment-major layout (contiguous 1 KB per load).
template <int CPW, bool BN, bool BIAS, bool XBF16, bool VBF16>
__global__ __launch_bounds__(256) void gemm_mfma2_kernel(
    const void* __restrict__ X, const unsigned short* __restrict__ WT,
    const unsigned short* __restrict__ LT, const float* __restrict__ bias,
    const float* __restrict__ scale, const float* __restrict__ shift,
    const float* __restrict__ dso, unsigned short* __restrict__ U, void* __restrict__ V,
    int N, int upitch, int ucols, int vpitch, int vcols) {
    constexpr int NCT = CPW / 16;
    __shared__ __align__(16) unsigned short Xs[64][128];  // 16 KB, granule-swizzled
    const int tid = threadIdx.x;
    const long rb = (long)blockIdx.x * 64;

#pragma unroll
    for (int i = 0; i < 4; ++i) {
        const int idx = i * 256 + tid;
        const int r = idx >> 4, g = idx & 15;
        const long gr = rb + r;
        float xs[8];
        if (gr < N) {
            if (XBF16) {
                const unsigned short* Xh = (const unsigned short*)X;
                short8 raw = *(const short8*)&Xh[gr * 128 + g * 8];
#pragma unroll
                for (int j = 0; j < 8; ++j) xs[j] = bf2f((unsigned short)raw[j]);
            } else {
                const float* Xf = (const float*)X;
                float4 a0 = *(const float4*)&Xf[gr * 128 + g * 8];
                float4 a1 = *(const float4*)&Xf[gr * 128 + g * 8 + 4];
                xs[0] = a0.x; xs[1] = a0.y; xs[2] = a0.z; xs[3] = a0.w;
                xs[4] = a1.x; xs[5] = a1.y; xs[6] = a1.z; xs[7] = a1.w;
            }
            if (BN) {
                float4 s0 = *(const float4*)&scale[g * 8];
                float4 s1 = *(const float4*)&scale[g * 8 + 4];
                float4 h0 = *(const float4*)&shift[g * 8];
                float4 h1 = *(const float4*)&shift[g * 8 + 4];
                float ss[8] = {s0.x, s0.y, s0.z, s0.w, s1.x, s1.y, s1.z, s1.w};
                float hh[8] = {h0.x, h0.y, h0.z, h0.w, h1.x, h1.y, h1.z, h1.w};
#pragma unroll
                for (int j = 0; j < 8; ++j) xs[j] = fmaxf(fmaf(xs[j], ss[j], hh[j]), 0.0f);
            }
        } else {
#pragma unroll
            for (int j = 0; j < 8; ++j) xs[j] = 0.0f;
        }
        short8 pk;
#pragma unroll
        for (int j = 0; j < 8; ++j) pk[j] = f2bf(xs[j]);
        const int gp = g ^ (r & 7);
        *(short8*)&Xs[r][gp * 8] = pk;
    }

    const int w = tid >> 6, l = tid & 63;
    const int lr = l & 15, kg = l >> 4;
    const unsigned short* BT = (w < 2) ? WT : LT;
    const int h = w & 1;
    const int c0 = h * CPW;
    short8 bfr[NCT][4];
#pragma unroll
    for (int ct = 0; ct < NCT; ++ct)
#pragma unroll
        for (int kc = 0; kc < 4; ++kc)
            bfr[ct][kc] = *(const short8*)&BT[((((h * NCT + ct) << 2) + kc) << 9) + (l << 3)];

    __syncthreads();

#pragma unroll 1
    for (int rt = 0; rt < 4; ++rt) {
        f32x4 acc[NCT];
#pragma unroll
        for (int ct = 0; ct < NCT; ++ct) acc[ct] = (f32x4)(0.0f);
        const int xrow = rt * 16 + lr;
#pragma unroll
        for (int kc = 0; kc < 4; ++kc) {
            const int p = (kc * 4 + kg) ^ (lr & 7);
            short8 av = *(const short8*)&Xs[xrow][p * 8];
#pragma unroll
            for (int ct = 0; ct < NCT; ++ct)
                acc[ct] = __builtin_amdgcn_mfma_f32_16x16x32_bf16(av, bfr[ct][kc], acc[ct], 0, 0, 0);
        }
        // epilogue: C/D layout col=lane&15, row=(lane>>4)*4+reg
        const long r0 = rb + rt * 16 + kg * 4;
        if (w < 2) {
#pragma unroll
            for (int ct = 0; ct < NCT; ++ct) {
                const int c = c0 + ct * 16 + lr;
                if (c < ucols) {
#pragma unroll
                    for (int r = 0; r < 4; ++r) {
                        const long rr = r0 + r;
                        if (rr < N) U[rr * upitch + c] = (unsigned short)f2bf(acc[ct][r] * dso[rr]);
                    }
                }
            }
        } else {
#pragma unroll
            for (int ct = 0; ct < NCT; ++ct) {
                const int c = c0 + ct * 16 + lr;
                if (c < vcols) {
#pragma unroll
                    for (int r = 0; r < 4; ++r) {
                        const long rr = r0 + r;
                        if (rr < N) {
                            float v = acc[ct][r];
                            if (BIAS) v += bias[c];
                            if (VBF16)
                                ((unsigned short*)V)[rr * vpitch + c] = (unsigned short)f2bf(v);
                            else
                                ((float*)V)[rr * vpitch + c] = v;
                        }
                    }
                }
            }
        }
    }
}

// ---------------------------------------------------------------- SpMM v3 (R14 config: bf16 gather, NPW nodes/wave, LDS reduce)
// Wave handles NPW nodes in disjoint lane sub-groups (LPN = 64/NPW lanes each).
// Y[n][0..D) = dsi[n] * sum_e Uin[eidx_e][0..D) + addB[n][0..D)
// BF16IO: addB/Y bf16 (pitch D) else f32. UCH = useful channels in Uin rows.
template <int D, int PITCH, int LPR, bool BF16IO, int UCH, int NPW>
__global__ __launch_bounds__(256) void spmm_bf16_kernel(
    const unsigned short* __restrict__ Uin, const void* __restrict__ addB,
    void* __restrict__ Y, const int* __restrict__ eidx, const int* __restrict__ rs,
    const int* __restrict__ deg, const float* __restrict__ dsi, int N) {
    constexpr int LPN = 64 / NPW;   // lanes per node
    constexpr int G = LPN / LPR;    // edge groups per node
    __shared__ __align__(16) int sE[4][64];
    __shared__ __align__(16) float sR[4][64][8];
    const int wvloc = threadIdx.x >> 6;
    const int lane = threadIdx.x & 63;
    const int ll = lane & (LPN - 1);       // lane within node group
    const int nbase = lane - ll;           // node group base lane
    const int lr = ll & (LPR - 1);         // position within row
    const int g = ll / LPR;                // edge group within node
    const int wv = (blockIdx.x * 4 + wvloc) * NPW + (lane / LPN);
    if (wv >= N) return;
    const bool act = (UCH == LPR * 8) || (lr * 8 < UCH);
    const int start = rs[wv];
    const int dg = deg[wv];
    const float di = dsi[wv];
    float acc[8] = {};
    for (int j0 = 0; j0 < dg; j0 += LPN) {
        const int m = min(LPN, dg - j0);
        if (ll < m) sE[wvloc][lane] = eidx[start + j0 + ll];
        asm volatile("s_waitcnt lgkmcnt(0)" ::: "memory");
        int j = g;
#pragma unroll 1
        for (; j + 3 * G < m; j += 4 * G) {
            if (act) {
                const int s0 = sE[wvloc][nbase + j];
                const int s1 = sE[wvloc][nbase + j + G];
                const int s2 = sE[wvloc][nbase + j + 2 * G];
                const int s3 = sE[wvloc][nbase + j + 3 * G];
                const uint4 p0 = *(const uint4*)&Uin[(long)s0 * PITCH + lr * 8];
                const uint4 p1 = *(const uint4*)&Uin[(long)s1 * PITCH + lr * 8];
                const uint4 p2 = *(const uint4*)&Uin[(long)s2 * PITCH + lr * 8];
                const uint4 p3 = *(const uint4*)&Uin[(long)s3 * PITCH + lr * 8];
                acc8(p0, acc);
                acc8(p1, acc);
                acc8(p2, acc);
                acc8(p3, acc);
            }
        }
#pragma unroll 1
        for (; j < m; j += G) {
            if (act) {
                const int s = sE[wvloc][nbase + j];
                const uint4 p = *(const uint4*)&Uin[(long)s * PITCH + lr * 8];
                acc8(p, acc);
            }
        }
        asm volatile("s_waitcnt lgkmcnt(0)" ::: "memory");
    }
    // cross-group reduce via LDS (per node, over its G groups)
    {
        f32x4 t0 = {acc[0], acc[1], acc[2], acc[3]};
        f32x4 t1 = {acc[4], acc[5], acc[6], acc[7]};
        *(f32x4*)&sR[wvloc][lane][0] = t0;
        *(f32x4*)&sR[wvloc][lane][4] = t1;
    }
    asm volatile("s_waitcnt lgkmcnt(0)" ::: "memory");
    if (ll < LPR && ll * 8 < D) {
        f32x4 r0 = (f32x4)(0.0f), r1 = (f32x4)(0.0f);
#pragma unroll
        for (int g2 = 0; g2 < G; ++g2) {
            const float* q = &sR[wvloc][nbase + g2 * LPR + ll][0];
            r0 += *(const f32x4*)&q[0];
            r1 += *(const f32x4*)&q[4];
        }
        const long o = (long)wv * D + ll * 8;
        if (BF16IO) {
            const unsigned short* ab = (const unsigned short*)addB;
            short8 braw = *(const short8*)&ab[o];
            short8 yv;
#pragma unroll
            for (int j = 0; j < 4; ++j)
                yv[j] = f2bf(bf2f((unsigned short)braw[j]) + r0[j] * di);
#pragma unroll
            for (int j = 0; j < 4; ++j)
                yv[4 + j] = f2bf(bf2f((unsigned short)braw[4 + j]) + r1[j] * di);
            *(short8*)&((unsigned short*)Y)[o] = yv;
        } else {
            const float* ab = (const float*)addB;
            f32x4 b0 = *(const f32x4*)&ab[o];
            f32x4 b1 = *(const f32x4*)&ab[o + 4];
            f32x4 y0 = b0 + r0 * di;
            f32x4 y1 = b1 + r1 * di;
            *(f32x4*)&((float*)Y)[o] = y0;
            *(f32x4*)&((float*)Y)[o + 4] = y1;
        }
    }
}

// ---------------------------------------------------------------- BN stats over bf16 P (sum, sumsq per channel)
__global__ __launch_bounds__(256) void bnstats_kernel(const unsigned short* __restrict__ P,
                                                      float* __restrict__ sum,
                                                      float* __restrict__ sq, int N) {
    int c = threadIdx.x & 127;
    int half = threadIdx.x >> 7;
    float s = 0.f, q = 0.f;
    for (long r = blockIdx.x * 2 + half; r < N; r += gridDim.x * 2) {
        float v = bf2f(P[r * 128 + c]);
        s += v;
        q += v * v;
    }
    __shared__ float ls[256], lq[256];
    ls[threadIdx.x] = s;
    lq[threadIdx.x] = q;
    __syncthreads();
    if (threadIdx.x < 128) {
        s = ls[threadIdx.x] + ls[threadIdx.x + 128];
        q = lq[threadIdx.x] + lq[threadIdx.x + 128];
        atomicAdd(&sum[c], s);
        atomicAdd(&sq[c], q);
    }
}

// bnfinal also re-zeroes sum/sq (so the next bnstats needs no memset; replay-safe)
__global__ void bnfinal_kernel(float* __restrict__ sum, float* __restrict__ sq,
                               const float* __restrict__ g, const float* __restrict__ be,
                               float* __restrict__ scale, float* __restrict__ shift, float invN) {
    int c = threadIdx.x;  // 128 threads
    float mu = sum[c] * invN;
    float var = sq[c] * invN - mu * mu;
    float sc = g[c] * rsqrtf(var + 1e-5f);
    scale[c] = sc;
    shift[c] = be[c] - mu * sc;
    sum[c] = 0.0f;
    sq[c] = 0.0f;
}

// ---------------------------------------------------------------- launch
extern "C" void kernel_launch(void* const* d_in, const int* in_sizes, int n_in,
                              void* d_out, int out_size, void* d_ws, size_t ws_size,
                              hipStream_t stream) {
    const float* feat = (const float*)d_in[0];
    const int* src = (const int*)d_in[1];
    const int* dst = (const int*)d_in[2];
    const float* W0 = (const float*)d_in[3];
    const float* L0 = (const float*)d_in[4];
    const float* W1 = (const float*)d_in[5];
    const float* L1 = (const float*)d_in[6];
    const float* W2 = (const float*)d_in[7];
    const float* L2 = (const float*)d_in[8];
    const float* b2 = (const float*)d_in[9];
    const float* g0 = (const float*)d_in[10];
    const float* be0 = (const float*)d_in[11];
    const float* g1 = (const float*)d_in[12];
    const float* be1 = (const float*)d_in[13];
    float* out = (float*)d_out;

    char* w = (char*)d_ws;
    unsigned short* bufP = (unsigned short*)(w + 0);          // 25,600,000 B (bf16 P0/P1)
    unsigned short* bufU = (unsigned short*)(w + 25600000);   // 25,600,000 B (bf16 U)
    unsigned short* bufV = (unsigned short*)(w + 51200000);   // 25,600,000 B (bf16 V, layers 0/1)
    float* V2 = (float*)(w + 51200000);                       // 16,000,000 B (layer2 V f32; aliases bufV, dead then)
    int* eidx = (int*)(w + 76800000);                         // 6,400,000 B
    int* ind = (int*)(w + 83200000);                          // 400,000 B
    float* dso = (float*)(w + 83600000);                      // 400,000 B
    float* dsi = (float*)(w + 84000000);                      // 400,000 B
    int* rs = (int*)(w + 84400000);                           // 400,000 B
    int* bsum = (int*)(w + 84800000);                         // 512 B
    float* bnsum = (float*)(w + 84801024);                    // 512 B
    float* bnsq = (float*)(w + 84801536);                     // 512 B
    float* scl = (float*)(w + 84802048);                      // 512 B
    float* sht = (float*)(w + 84802560);                      // 512 B
    unsigned short* W0T = (unsigned short*)(w + 84803072);    // 32768 B each (fragment-major)
    unsigned short* L0T = (unsigned short*)(w + 84835840);
    unsigned short* W1T = (unsigned short*)(w + 84868608);
    unsigned short* L1T = (unsigned short*)(w + 84901376);
    unsigned short* W2T = (unsigned short*)(w + 84934144);    // 16384 B each (npad=64)
    unsigned short* L2T = (unsigned short*)(w + 84950528);

    // uint16 H matrices (NCHUNK=64: 12.8 MB each) alias later-written buffers:
    unsigned short* Hout = bufP;  // dead after redscan; bufP first written by spmm0
    unsigned short* Hin = bufU;   // dead after fill; bufU first written by gemm0 (after fill)

    const int N = NN;
    const int NB = (N + 1023) / 1024;  // 98
    const int GB = (N + 63) / 64;      // 1563 gemm blocks
    const int SB2 = (N + 7) / 8;       // 12500 spmm blocks (4 waves x 2 nodes)

    // weight prep (independent of graph build)
    PrepBatch pb;
    pb.src[0] = W0; pb.dst[0] = W0T; pb.nout[0] = 128; pb.npad[0] = 128;
    pb.src[1] = L0; pb.dst[1] = L0T; pb.nout[1] = 128; pb.npad[1] = 128;
    pb.src[2] = W1; pb.dst[2] = W1T; pb.nout[2] = 128; pb.npad[2] = 128;
    pb.src[3] = L1; pb.dst[3] = L1T; pb.nout[3] = 128; pb.npad[3] = 128;
    pb.src[4] = W2; pb.dst[4] = W2T; pb.nout[4] = 40;  pb.npad[4] = 64;
    pb.src[5] = L2; pb.dst[5] = L2T; pb.nout[5] = 40;  pb.npad[5] = 64;
    prep_kernel<<<dim3(64, 6), 256, 0, stream>>>(pb);

    // graph build (no global atomics; range-paired histograms, NCHUNK=64)
    hist_kernel<<<dim3(NCHUNK, NRPAIR, 2), 512, 0, stream>>>(src, dst, Hout, Hin);
    redscan_kernel<<<(N + 255) / 256, 256, 0, stream>>>(Hout, Hin, ind, dso, dsi);
    scan1_kernel<<<NB, 256, 0, stream>>>(ind, rs, bsum, N);
    scan2_kernel<<<1, 128, 0, stream>>>(bsum, NB);
    scan3_kernel<<<(N + 255) / 256, 256, 0, stream>>>(rs, ind, bsum, N);
    fill_kernel<<<NCHUNK * NRPAIR, 512, 0, stream>>>(src, dst, Hin, rs, eidx);

    // zero BN accumulators once; bnfinal re-zeroes after each use
    hipMemsetAsync(bnsum, 0, 1024, stream);

    // ---- layer 0: U0 = dso*(feat@W0) -> bufU, V0 = feat@L0 -> bufV (bf16); P0 = spmm(U0)+V0 -> bufP (bf16)
    gemm_mfma2_kernel<64, false, false, false, true><<<GB, 256, 0, stream>>>(
        feat, W0T, L0T, nullptr, nullptr, nullptr, dso, bufU, bufV, N, 128, 128, 128, 128);
    spmm_bf16_kernel<128, 128, 16, true, 128, 2><<<SB2, 256, 0, stream>>>(
        bufU, bufV, bufP, eidx, rs, ind, dsi, N);
    bnstats_kernel<<<1024, 256, 0, stream>>>(bufP, bnsum, bnsq, N);
    bnfinal_kernel<<<1, 128, 0, stream>>>(bnsum, bnsq, g0, be0, scl, sht, 1.0f / N);

    // ---- layer 1: X = bnrelu(P0) bf16; U -> bufU, V -> bufV; P1 = spmm+V -> bufP
    gemm_mfma2_kernel<64, true, false, true, true><<<GB, 256, 0, stream>>>(
        bufP, W1T, L1T, nullptr, scl, sht, dso, bufU, bufV, N, 128, 128, 128, 128);
    spmm_bf16_kernel<128, 128, 16, true, 128, 2><<<SB2, 256, 0, stream>>>(
        bufU, bufV, bufP, eidx, rs, ind, dsi, N);
    bnstats_kernel<<<1024, 256, 0, stream>>>(bufP, bnsum, bnsq, N);
    bnfinal_kernel<<<1, 128, 0, stream>>>(bnsum, bnsq, g1, be1, scl, sht, 1.0f / N);

    // ---- layer 2: U2 pitch 40 bf16 (cols 0..39) -> bufU, V2 = X@L2 + b2 (f32, pitch 40)
    gemm_mfma2_kernel<32, true, true, true, false><<<GB, 256, 0, stream>>>(
        bufP, W2T, L2T, b2, scl, sht, dso, bufU, V2, N, 40, 40, 40, 40);
    spmm_bf16_kernel<40, 40, 8, false, 40, 2><<<SB2, 256, 0, stream>>>(
        bufU, V2, out, eidx, rs, ind, dsi, N);
}